// Round 2
// baseline (1578.257 us; speedup 1.0000x reference)
//
#include <hip/hip_runtime.h>
#include <math.h>

#define CC 32

static inline int cdiv(long long a, int b) { return (int)((a + b - 1) / b); }

// ---------- degree / normalization ----------
__global__ void k_deg(const int* __restrict__ src, float* __restrict__ deg, int E) {
  int i = blockIdx.x * blockDim.x + threadIdx.x;
  if (i < E) atomicAdd(&deg[src[i]], 1.0f);
}

__global__ void k_dis(float* __restrict__ dis, int N) {
  int i = blockIdx.x * blockDim.x + threadIdx.x;
  if (i < N) {
    float d = dis[i];
    dis[i] = (d > 0.f) ? rsqrtf(fmaxf(d, 1.f)) : 0.f;
  }
}

// ---------- Chebyshev propagation: out[dst] += scale * (-dis[s]*dis[d]) * x[src] ----------
__global__ void k_prop(const float* __restrict__ x, const int* __restrict__ src,
                       const int* __restrict__ dst, const float* __restrict__ dis,
                       float scale, float* __restrict__ out, int E) {
  int tid = blockIdx.x * blockDim.x + threadIdx.x;
  if (tid < E * CC) {
    int e = tid >> 5, c = tid & 31;
    int s = src[e], d = dst[e];
    float w = scale * (-dis[s] * dis[d]);
    atomicAdd(&out[(long long)d * CC + c], w * x[(long long)s * CC + c]);
  }
}

// out[i] = -in[i]  (in-place safe)
__global__ void k_neg(float* __restrict__ out, const float* __restrict__ in, int n) {
  int i = blockIdx.x * blockDim.x + threadIdx.x;
  if (i < n) out[i] = -in[i];
}

// out[i][j] (32-wide rows in T, OUTC-wide rows in out) (+)= T[i][:] @ W[32][OUTC]
template <int OUTC>
__global__ void k_gemm(const float* __restrict__ T, const float* __restrict__ W,
                       float* __restrict__ out, int N, int accumulate) {
  __shared__ float w[32 * OUTC];
  for (int i = threadIdx.x; i < 32 * OUTC; i += blockDim.x) w[i] = W[i];
  __syncthreads();
  const int ROWS = 256 / OUTC;
  int row = blockIdx.x * ROWS + threadIdx.x / OUTC;
  int col = threadIdx.x % OUTC;
  if (row >= N) return;
  const float* tr = T + (long long)row * 32;
  float acc = 0.f;
#pragma unroll
  for (int c = 0; c < 32; ++c) acc += tr[c] * w[c * OUTC + col];
  float* o = out + (long long)row * OUTC + col;
  if (accumulate) *o += acc; else *o = acc;
}

__global__ void k_chebinit(float* __restrict__ out, const float* __restrict__ b, int n) {
  int i = blockIdx.x * blockDim.x + threadIdx.x;
  if (i < n) out[i] = b[i & 31];
}

// ---------- SuperGAT ----------
__global__ void k_mxinit(unsigned* __restrict__ mx, int n) {
  int i = blockIdx.x * blockDim.x + threadIdx.x;
  if (i < n) mx[i] = 0x007FFFFFu;  // encode(-inf)
}

__device__ inline unsigned enc_f(float f) {
  unsigned u = __float_as_uint(f);
  return u ^ ((u & 0x80000000u) ? 0xFFFFFFFFu : 0x80000000u);
}
__device__ inline float dec_f(unsigned k) {
  return (k & 0x80000000u) ? __uint_as_float(k ^ 0x80000000u) : __uint_as_float(~k);
}

// one thread per (edge, head); edges >= E are self-loops
__global__ void k_alpha(const float* __restrict__ h, const int* __restrict__ src,
                        const int* __restrict__ dst, const float* __restrict__ attl,
                        const float* __restrict__ attr, float* __restrict__ alpha,
                        unsigned* __restrict__ mx, int E, int N) {
  int idx = blockIdx.x * blockDim.x + threadIdx.x;
  int tot = (E + N) * 2;
  if (idx >= tot) return;
  int e = idx >> 1, hd = idx & 1;
  int s = (e < E) ? src[e] : (e - E);
  int d = (e < E) ? dst[e] : (e - E);
  const float4* xj = (const float4*)(h + (long long)s * 64 + hd * 32);
  const float4* xi = (const float4*)(h + (long long)d * 64 + hd * 32);
  const float4* al = (const float4*)(attl + hd * 32);
  const float4* ar = (const float4*)(attr + hd * 32);
  float lg = 0.f, a = 0.f;
#pragma unroll
  for (int q = 0; q < 8; ++q) {
    float4 j = xj[q], i2 = xi[q], l = al[q], r = ar[q];
    lg += j.x * i2.x + j.y * i2.y + j.z * i2.z + j.w * i2.w;
    a += j.x * l.x + j.y * l.y + j.z * l.z + j.w * l.w;
    a += i2.x * r.x + i2.y * r.y + i2.z * r.z + i2.w * r.w;
  }
  float sg = 1.f / (1.f + __expf(-lg));
  a *= sg;
  a = (a > 0.f) ? a : 0.2f * a;  // leaky_relu 0.2
  alpha[idx] = a;
  atomicMax(&mx[d * 2 + hd], enc_f(a));
}

__global__ void k_expsum(const int* __restrict__ dst, float* __restrict__ alpha,
                         const unsigned* __restrict__ mx, float* __restrict__ sm,
                         int E, int N) {
  int idx = blockIdx.x * blockDim.x + threadIdx.x;
  int tot = (E + N) * 2;
  if (idx >= tot) return;
  int e = idx >> 1, hd = idx & 1;
  int d = (e < E) ? dst[e] : (e - E);
  float m = dec_f(mx[d * 2 + hd]);
  float ev = __expf(alpha[idx] - m);
  alpha[idx] = ev;
  atomicAdd(&sm[d * 2 + hd], ev);
}

// one thread per (edge, channel): head-fused mean accumulate into acc[N][32]
__global__ void k_scatter(const float* __restrict__ h, const int* __restrict__ src,
                          const int* __restrict__ dst, const float* __restrict__ alpha,
                          const float* __restrict__ sm, float* __restrict__ acc,
                          int E, int N) {
  long long tid = (long long)blockIdx.x * blockDim.x + threadIdx.x;
  long long tot = (long long)(E + N) * 32;
  if (tid >= tot) return;
  int e = (int)(tid >> 5);
  int c = (int)(tid & 31);
  int s = (e < E) ? src[e] : (e - E);
  int d = (e < E) ? dst[e] : (e - E);
  float a0 = alpha[e * 2] / sm[d * 2];
  float a1 = alpha[e * 2 + 1] / sm[d * 2 + 1];
  float v = 0.5f * (h[(long long)s * 64 + c] * a0 + h[(long long)s * 64 + 32 + c] * a1);
  atomicAdd(&acc[(long long)d * 32 + c], v);
}

// y = leaky(x2,0.01)+x2 where x2 = head-mean + bias; also BN partial sums
__global__ void k_finup(const float* __restrict__ acc, const float* __restrict__ gb,
                        float* __restrict__ y, float* __restrict__ bns, int N) {
  __shared__ float ls[64];
  if (threadIdx.x < 64) ls[threadIdx.x] = 0.f;
  __syncthreads();
  int tx = threadIdx.x & 31, ty = threadIdx.x >> 5;
  int base = blockIdx.x * 64;
  float ps = 0.f, pq = 0.f;
#pragma unroll
  for (int it = 0; it < 8; ++it) {
    int row = base + it * 8 + ty;
    if (row < N) {
      float v = acc[(long long)row * 32 + tx] + gb[tx];
      float yv = ((v > 0.f) ? v : 0.01f * v) + v;
      y[(long long)row * 32 + tx] = yv;
      ps += yv;
      pq += yv * yv;
    }
  }
  atomicAdd(&ls[tx], ps);
  atomicAdd(&ls[32 + tx], pq);
  __syncthreads();
  if (threadIdx.x < 64) atomicAdd(&bns[threadIdx.x], ls[threadIdx.x]);
}

// in-place safe (y may alias out)
__global__ void k_bnfinal(const float* __restrict__ y, const float* __restrict__ bns,
                          const float* __restrict__ g, const float* __restrict__ b,
                          float* __restrict__ out, int N) {
  int i = blockIdx.x * blockDim.x + threadIdx.x;
  if (i >= N * CC) return;
  int c = i & 31;
  float inv_n = 1.f / (float)N;
  float mu = bns[c] * inv_n;
  float var = bns[32 + c] * inv_n - mu * mu;
  out[i] = (y[i] - mu) * rsqrtf(var + 1e-5f) * g[c] + b[c];
}

extern "C" void kernel_launch(void* const* d_in, const int* in_sizes, int n_in,
                              void* d_out, int out_size, void* d_ws, size_t ws_size,
                              hipStream_t stream) {
  const float* patch = (const float*)d_in[0];
  const int* eidx = (const int*)d_in[1];
  // d_in[2] = edge_attr (unused by reference)
  const float* cheb_w = (const float*)d_in[3];
  const float* cheb_b = (const float*)d_in[4];
  const float* lin_w = (const float*)d_in[5];
  const float* att_l = (const float*)d_in[6];
  const float* att_r = (const float*)d_in[7];
  const float* gat_b = (const float*)d_in[8];
  const float* bn_g = (const float*)d_in[9];
  const float* bn_b = (const float*)d_in[10];
  float* out = (float*)d_out;

  const int N = in_sizes[0] / CC;   // 100000
  const int E = in_sizes[1] / 2;    // 1600000
  const int* src = eidx;
  const int* dst = eidx + E;

  // workspace layout (total ~13.5M floats = 54.1 MB)
  float* f = (float*)d_ws;
  float* R2 = f;                             // N*32  (gat accmean) — first so R2+R0 memset fuses
  float* R0 = R2 + (size_t)N * 32;           // N*32  (Tx ping)
  float* R1 = R0 + (size_t)N * 32;           // N*32  (Tx pong; R0..R1 contiguous -> h[N*64])
  float* alpha = R1 + (size_t)N * 32;        // (E+N)*2
  unsigned* mx = (unsigned*)(alpha + (size_t)(E + N) * 2);  // N*2
  float* sm = (float*)(mx + (size_t)N * 2);  // N*2
  float* dis = sm + (size_t)N * 2;           // N
  float* bns = dis + N;                      // 64
  float* h = R0;                             // N*64 overlays R0..R1 after cheb

  const int B = 256;
  const long long NC = (long long)N * 32;

  // zero accumulators: R2+R0 contiguous; sm..bns contiguous
  hipMemsetAsync(R2, 0, sizeof(float) * (size_t)N * 64, stream);            // R2, R0
  hipMemsetAsync(sm, 0, sizeof(float) * ((size_t)N * 3 + 64), stream);      // sm, dis, bns

  // degree / dis
  k_deg<<<cdiv(E, B), B, 0, stream>>>(src, dis, E);
  k_dis<<<cdiv(N, B), B, 0, stream>>>(dis, N);

  // ChebConv into d_out (x lives in d_out until h is computed)
  k_chebinit<<<cdiv(NC, B), B, 0, stream>>>(out, cheb_b, N * 32);
  k_gemm<32><<<cdiv(N, 8), B, 0, stream>>>(patch, cheb_w + 0 * 1024, out, N, 1);
  // Tx1 -> R0 (zeroed)
  k_prop<<<cdiv((long long)E * 32, B), B, 0, stream>>>(patch, src, dst, dis, 1.f, R0, E);
  k_gemm<32><<<cdiv(N, 8), B, 0, stream>>>(R0, cheb_w + 1 * 1024, out, N, 1);
  // Tx2 = 2*prop(Tx1) - Tx0 : R1 = -patch, then += 2*w*R0[src]
  k_neg<<<cdiv(NC, B), B, 0, stream>>>(R1, patch, N * 32);
  k_prop<<<cdiv((long long)E * 32, B), B, 0, stream>>>(R0, src, dst, dis, 2.f, R1, E);
  k_gemm<32><<<cdiv(N, 8), B, 0, stream>>>(R1, cheb_w + 2 * 1024, out, N, 1);
  // Tx3: R0 = -R0 (=-Tx1), then += 2*w*R1[src]
  k_neg<<<cdiv(NC, B), B, 0, stream>>>(R0, R0, N * 32);
  k_prop<<<cdiv((long long)E * 32, B), B, 0, stream>>>(R1, src, dst, dis, 2.f, R0, E);
  k_gemm<32><<<cdiv(N, 8), B, 0, stream>>>(R0, cheb_w + 3 * 1024, out, N, 1);
  // Tx4: R1 = -R1 (=-Tx2), then += 2*w*R0[src]
  k_neg<<<cdiv(NC, B), B, 0, stream>>>(R1, R1, N * 32);
  k_prop<<<cdiv((long long)E * 32, B), B, 0, stream>>>(R0, src, dst, dis, 2.f, R1, E);
  k_gemm<32><<<cdiv(N, 8), B, 0, stream>>>(R1, cheb_w + 4 * 1024, out, N, 1);

  // SuperGAT: h = x @ lin_w  (x in d_out; h overlays R0..R1)
  k_gemm<64><<<cdiv(N, 4), B, 0, stream>>>(out, lin_w, h, N, 0);
  k_mxinit<<<cdiv(N * 2, B), B, 0, stream>>>(mx, N * 2);
  int tot_eh = (E + N) * 2;
  k_alpha<<<cdiv(tot_eh, B), B, 0, stream>>>(h, src, dst, att_l, att_r, alpha, mx, E, N);
  k_expsum<<<cdiv(tot_eh, B), B, 0, stream>>>(dst, alpha, mx, sm, E, N);
  k_scatter<<<cdiv((long long)(E + N) * 32, B), B, 0, stream>>>(h, src, dst, alpha, sm, R2, E, N);

  // y into d_out (x dead), BN stats, finalize in place
  k_finup<<<cdiv(N, 64), B, 0, stream>>>(R2, gat_b, out, bns, N);
  k_bnfinal<<<cdiv(NC, B), B, 0, stream>>>(out, bns, bn_g, bn_b, out, N);
}